// Round 1
// baseline (229.949 us; speedup 1.0000x reference)
//
#include <hip/hip_runtime.h>
#include <math.h>

#define B_ROWS 8192
#define DIM 64
#define NCODES 2048
#define NTILES 16
#define TILE_C (NCODES / NTILES)   // 128 codes per tile
#define ROWS_PER_CBLOCK 256
#define EPSF 1e-6f
#define BETA 0.25f
#define V_VAL 0.125f               // 1/sqrt(64)

__device__ __forceinline__ float wave_sum64(float v) {
#pragma unroll
    for (int m = 32; m >= 1; m >>= 1) v += __shfl_xor(v, m, 64);
    return v;
}

// Kernel A: per-code squared norms; also zero the loss accumulator.
__global__ void rq_prep_codes(const float* __restrict__ codes,
                              float* __restrict__ cn,
                              float* __restrict__ loss_out) {
    int tid = threadIdx.x;
    int lane = tid & 63;
    int c = blockIdx.x * 4 + (tid >> 6);
    float cv = codes[(size_t)c * DIM + lane];
    float s = wave_sum64(cv * cv);
    if (lane == 0) cn[c] = s;
    if (blockIdx.x == 0 && tid == 0) *loss_out = 0.0f;
}

// Kernel B: per-row rotation factors + x_canonical = R^T x.
// R = I + A + A^2/(1+d+eps), A = u v^T - v u^T  (antisymmetric)
// R^T x = x + u*(-b + (d*b - a)/den) + v*(a - (b - d*a)/den)
//   with a = u.x, b = v.x, d = u.v, den = 1 + d + eps
__global__ void rq_prep_rows(const float* __restrict__ x,
                             const float* __restrict__ pq,
                             float* __restrict__ xc,
                             float* __restrict__ uo,
                             float* __restrict__ duv) {
    int tid = threadIdx.x;
    int lane = tid & 63;
    int r = blockIdx.x * 4 + (tid >> 6);
    float xv = x[(size_t)r * DIM + lane];
    float qv = pq[(size_t)r * DIM + lane];
    float n2 = wave_sum64(qv * qv);
    float inv = 1.0f / fmaxf(sqrtf(n2), EPSF);
    float uv = qv * inv;
    float d = V_VAL * wave_sum64(uv);
    float a = wave_sum64(uv * xv);
    float b = V_VAL * wave_sum64(xv);
    float den = 1.0f + d + EPSF;
    float cu = -b + (d * b - a) / den;
    float cv = a - (b - d * a) / den;
    float xcv = xv + uv * cu + V_VAL * cv;
    xc[(size_t)r * DIM + lane] = xcv;
    uo[(size_t)r * DIM + lane] = uv;
    if (lane == 0) duv[r] = d;
}

// Kernel C: fp32 distance scan. Each thread owns one row (x_canonical in 64
// VGPRs), streams a 128-code tile with wave-uniform loads. score = |c|^2 - 2 x.c
// (the per-row |x|^2 constant cannot change the argmin). Strict < ascending
// scan == jnp.argmin first-min tie-break.
__global__ __launch_bounds__(256) void rq_dist_argmin(
        const float* __restrict__ xc,
        const float* __restrict__ codes,
        const float* __restrict__ cn,
        float* __restrict__ pd,
        int* __restrict__ pi) {
    int tile = blockIdx.x & (NTILES - 1);
    int rblk = blockIdx.x / NTILES;
    int r = rblk * ROWS_PER_CBLOCK + threadIdx.x;

    float4 xr[16];
    const float4* xp = (const float4*)(xc + (size_t)r * DIM);
#pragma unroll
    for (int i = 0; i < 16; ++i) xr[i] = xp[i];

    int c0 = tile * TILE_C;
    float best = INFINITY;
    int bidx = 0x7fffffff;
    for (int c = 0; c < TILE_C; ++c) {
        const float* __restrict__ cp = codes + (size_t)(c0 + c) * DIM;
        float s0 = 0.f, s1 = 0.f, s2 = 0.f, s3 = 0.f;
#pragma unroll
        for (int i = 0; i < 16; ++i) {
            s0 = fmaf(xr[i].x, cp[4 * i + 0], s0);
            s1 = fmaf(xr[i].y, cp[4 * i + 1], s1);
            s2 = fmaf(xr[i].z, cp[4 * i + 2], s2);
            s3 = fmaf(xr[i].w, cp[4 * i + 3], s3);
        }
        float s = (s0 + s1) + (s2 + s3);
        float score = cn[c0 + c] - 2.0f * s;
        if (score < best) { best = score; bidx = c0 + c; }
    }
    pd[(size_t)tile * B_ROWS + r] = best;
    pi[(size_t)tile * B_ROWS + r] = bidx;
}

// Kernel D: combine the 16 partial argmins per row (lexicographic (dist,idx)
// min -> first-occurrence semantics), gather code, rotate back (R q), write
// quantized + index + loss contribution.
// R q = q + u*(bq + (d*bq - aq)/den) + v*(-aq - (bq - d*aq)/den)
__global__ void rq_epilogue(const float* __restrict__ x,
                            const float* __restrict__ codes,
                            const float* __restrict__ uo,
                            const float* __restrict__ duv,
                            const float* __restrict__ pd,
                            const int* __restrict__ pi,
                            float* __restrict__ out_q,
                            float* __restrict__ out_idx,
                            float* __restrict__ out_loss) {
    int tid = threadIdx.x;
    int lane = tid & 63;
    int r = blockIdx.x * 4 + (tid >> 6);

    float dmin = INFINITY;
    int imin = 0x7fffffff;
    if (lane < NTILES) {
        dmin = pd[(size_t)lane * B_ROWS + r];
        imin = pi[(size_t)lane * B_ROWS + r];
    }
#pragma unroll
    for (int m = 1; m < NTILES; m <<= 1) {
        float od = __shfl_xor(dmin, m, 64);
        int oi = __shfl_xor(imin, m, 64);
        if (od < dmin || (od == dmin && oi < imin)) { dmin = od; imin = oi; }
    }
    int idx = __shfl(imin, 0, 64);

    float qc = codes[(size_t)idx * DIM + lane];
    float uv = uo[(size_t)r * DIM + lane];
    float xv = x[(size_t)r * DIM + lane];
    float d = duv[r];

    float aq = wave_sum64(uv * qc);
    float bq = V_VAL * wave_sum64(qc);
    float den = 1.0f + d + EPSF;
    float cu = bq + (d * bq - aq) / den;
    float cv = -aq - (bq - d * aq) / den;
    float qout = qc + uv * cu + V_VAL * cv;
    out_q[(size_t)r * DIM + lane] = qout;

    float diff = xv - qc;
    float l = wave_sum64(diff * diff);
    if (lane == 0) {
        out_idx[r] = (float)idx;
        atomicAdd(out_loss, (1.0f + BETA) * l * (1.0f / (float)B_ROWS));
    }
}

extern "C" void kernel_launch(void* const* d_in, const int* in_sizes, int n_in,
                              void* d_out, int out_size, void* d_ws, size_t ws_size,
                              hipStream_t stream) {
    const float* x     = (const float*)d_in[0];
    const float* pq    = (const float*)d_in[1];
    const float* codes = (const float*)d_in[2];

    float* out      = (float*)d_out;
    float* out_q    = out;                         // B*D
    float* out_idx  = out + (size_t)B_ROWS * DIM;  // B (indices as float)
    float* out_loss = out_idx + B_ROWS;            // 1

    char* ws = (char*)d_ws;
    float* xc  = (float*)ws;                                        // 2 MB
    float* uo  = (float*)(ws + (size_t)2 * 1024 * 1024);            // 2 MB
    float* duv = (float*)(ws + (size_t)4 * 1024 * 1024);            // 32 KB
    float* cn  = (float*)(ws + (size_t)4 * 1024 * 1024 + 64 * 1024);// 8 KB
    float* pd  = (float*)(ws + (size_t)5 * 1024 * 1024);            // 512 KB
    int*   pi  = (int*)(ws + (size_t)5 * 1024 * 1024
                           + (size_t)NTILES * B_ROWS * 4);          // 512 KB

    rq_prep_codes<<<NCODES / 4, 256, 0, stream>>>(codes, cn, out_loss);
    rq_prep_rows<<<B_ROWS / 4, 256, 0, stream>>>(x, pq, xc, uo, duv);
    rq_dist_argmin<<<(B_ROWS / ROWS_PER_CBLOCK) * NTILES, 256, 0, stream>>>(
        xc, codes, cn, pd, pi);
    rq_epilogue<<<B_ROWS / 4, 256, 0, stream>>>(
        x, codes, uo, duv, pd, pi, out_q, out_idx, out_loss);
}

// Round 2
// 134.756 us; speedup vs baseline: 1.7064x; 1.7064x over previous
//
#include <hip/hip_runtime.h>
#include <math.h>

#define B_ROWS 8192
#define DIM 64
#define NCODES 2048
#define TILE_C 32                    // codes per block (staged in LDS)
#define NTILES (NCODES / TILE_C)     // 64 partial tiles -> one wave combines
#define ROWS_PER_BLOCK 512           // 256 threads x 2 rows
#define EPSF 1e-6f
#define BETA 0.25f
#define V_VAL 0.125f                 // 1/sqrt(64)

__device__ __forceinline__ float wave_sum64(float v) {
#pragma unroll
    for (int m = 32; m >= 1; m >>= 1) v += __shfl_xor(v, m, 64);
    return v;
}

// Kernel A: per-code squared norms.
__global__ void rq_prep_codes(const float* __restrict__ codes,
                              float* __restrict__ cn) {
    int tid = threadIdx.x;
    int lane = tid & 63;
    int c = blockIdx.x * 4 + (tid >> 6);
    float cv = codes[(size_t)c * DIM + lane];
    float s = wave_sum64(cv * cv);
    if (lane == 0) cn[c] = s;
}

// Kernel B: per-row rotation factors + x_canonical = R^T x (rank-2 update,
// never materialize R).  a=u.x, b=v.x, d=u.v, den=1+d+eps
__global__ void rq_prep_rows(const float* __restrict__ x,
                             const float* __restrict__ pq,
                             float* __restrict__ xc,
                             float* __restrict__ uo,
                             float* __restrict__ duv) {
    int tid = threadIdx.x;
    int lane = tid & 63;
    int r = blockIdx.x * 4 + (tid >> 6);
    float xv = x[(size_t)r * DIM + lane];
    float qv = pq[(size_t)r * DIM + lane];
    float n2 = wave_sum64(qv * qv);
    float inv = 1.0f / fmaxf(sqrtf(n2), EPSF);
    float uv = qv * inv;
    float d = V_VAL * wave_sum64(uv);
    float a = wave_sum64(uv * xv);
    float b = V_VAL * wave_sum64(xv);
    float den = 1.0f + d + EPSF;
    float cu = -b + (d * b - a) / den;
    float cv = a - (b - d * a) / den;
    float xcv = xv + uv * cu + V_VAL * cv;
    xc[(size_t)r * DIM + lane] = xcv;
    uo[(size_t)r * DIM + lane] = uv;
    if (lane == 0) duv[r] = d;
}

// Kernel C: fp32 distance scan. Block stages a 32-code tile into LDS (8 KB);
// each thread owns TWO rows in VGPRs and reuses every ds_read_b128 for 8 FMAs
// (DS 192 cyc vs VALU 256 cyc per code -> VALU-bound). LDS reads are
// wave-uniform -> broadcast, conflict-free. score = |c|^2 - 2 x.c; strict <
// ascending scan preserves jnp.argmin first-min tie-break.
__global__ __launch_bounds__(256) void rq_dist_argmin(
        const float* __restrict__ xc,
        const float* __restrict__ codes,
        const float* __restrict__ cn,
        float* __restrict__ pd,
        int* __restrict__ pi) {
    __shared__ float lds[TILE_C * DIM];

    int tile = blockIdx.x & (NTILES - 1);
    int rblk = blockIdx.x / NTILES;
    int t = threadIdx.x;
    int r0 = rblk * ROWS_PER_BLOCK + t;
    int r1 = r0 + 256;

    // stage 32 codes (2048 floats) -> 2 float4 per thread, coalesced
    {
        const float4* src = (const float4*)(codes + (size_t)tile * TILE_C * DIM);
        float4* dst = (float4*)lds;
        dst[t] = src[t];
        dst[t + 256] = src[t + 256];
    }

    float4 xa[16], xb[16];
    {
        const float4* xp0 = (const float4*)(xc + (size_t)r0 * DIM);
        const float4* xp1 = (const float4*)(xc + (size_t)r1 * DIM);
#pragma unroll
        for (int i = 0; i < 16; ++i) { xa[i] = xp0[i]; xb[i] = xp1[i]; }
    }
    __syncthreads();

    int c0 = tile * TILE_C;
    float best0 = INFINITY, best1 = INFINITY;
    int bi0 = 0x7fffffff, bi1 = 0x7fffffff;
#pragma unroll 4
    for (int c = 0; c < TILE_C; ++c) {
        const float4* cp = (const float4*)(lds + c * DIM);
        float a0 = 0.f, a1 = 0.f, b0 = 0.f, b1 = 0.f;
#pragma unroll
        for (int i = 0; i < 16; ++i) {
            float4 cv = cp[i];
            a0 = fmaf(xa[i].x, cv.x, a0);
            a1 = fmaf(xa[i].y, cv.y, a1);
            a0 = fmaf(xa[i].z, cv.z, a0);
            a1 = fmaf(xa[i].w, cv.w, a1);
            b0 = fmaf(xb[i].x, cv.x, b0);
            b1 = fmaf(xb[i].y, cv.y, b1);
            b0 = fmaf(xb[i].z, cv.z, b0);
            b1 = fmaf(xb[i].w, cv.w, b1);
        }
        float nrm = cn[c0 + c];
        float s0 = nrm - 2.0f * (a0 + a1);
        float s1 = nrm - 2.0f * (b0 + b1);
        if (s0 < best0) { best0 = s0; bi0 = c0 + c; }
        if (s1 < best1) { best1 = s1; bi1 = c0 + c; }
    }
    pd[(size_t)tile * B_ROWS + r0] = best0;
    pi[(size_t)tile * B_ROWS + r0] = bi0;
    pd[(size_t)tile * B_ROWS + r1] = best1;
    pi[(size_t)tile * B_ROWS + r1] = bi1;
}

// Kernel D: combine 64 partials per row (one per lane; lexicographic (d,idx)
// butterfly -> first-occurrence semantics), gather code, rotate back (R q),
// write quantized + index + per-row loss (NO atomics).
__global__ void rq_epilogue(const float* __restrict__ x,
                            const float* __restrict__ codes,
                            const float* __restrict__ uo,
                            const float* __restrict__ duv,
                            const float* __restrict__ pd,
                            const int* __restrict__ pi,
                            float* __restrict__ out_q,
                            float* __restrict__ out_idx,
                            float* __restrict__ lossbuf) {
    int tid = threadIdx.x;
    int lane = tid & 63;
    int r = blockIdx.x * 4 + (tid >> 6);

    float dmin = pd[(size_t)lane * B_ROWS + r];
    int imin = pi[(size_t)lane * B_ROWS + r];
#pragma unroll
    for (int m = 1; m < 64; m <<= 1) {
        float od = __shfl_xor(dmin, m, 64);
        int oi = __shfl_xor(imin, m, 64);
        if (od < dmin || (od == dmin && oi < imin)) { dmin = od; imin = oi; }
    }
    int idx = imin;  // all lanes agree after full butterfly

    float qc = codes[(size_t)idx * DIM + lane];
    float uv = uo[(size_t)r * DIM + lane];
    float xv = x[(size_t)r * DIM + lane];
    float d = duv[r];

    float aq = wave_sum64(uv * qc);
    float bq = V_VAL * wave_sum64(qc);
    float den = 1.0f + d + EPSF;
    float cu = bq + (d * bq - aq) / den;
    float cv = -aq - (bq - d * aq) / den;
    float qout = qc + uv * cu + V_VAL * cv;
    out_q[(size_t)r * DIM + lane] = qout;

    float diff = xv - qc;
    float l = wave_sum64(diff * diff);
    if (lane == 0) {
        out_idx[r] = (float)idx;
        lossbuf[r] = l;
    }
}

// Kernel E: single-block sum of 8192 per-row losses -> scaled scalar.
__global__ void rq_loss_reduce(const float* __restrict__ lossbuf,
                               float* __restrict__ out_loss) {
    __shared__ float part[16];
    int tid = threadIdx.x;  // 1024 threads
    float s = 0.f;
#pragma unroll
    for (int i = 0; i < B_ROWS / 1024; ++i) s += lossbuf[tid + i * 1024];
    s = wave_sum64(s);
    if ((tid & 63) == 0) part[tid >> 6] = s;
    __syncthreads();
    if (tid < 64) {
        float v = (tid < 16) ? part[tid] : 0.f;
        v = wave_sum64(v);
        if (tid == 0) *out_loss = v * (1.0f + BETA) * (1.0f / (float)B_ROWS);
    }
}

extern "C" void kernel_launch(void* const* d_in, const int* in_sizes, int n_in,
                              void* d_out, int out_size, void* d_ws, size_t ws_size,
                              hipStream_t stream) {
    const float* x     = (const float*)d_in[0];
    const float* pq    = (const float*)d_in[1];
    const float* codes = (const float*)d_in[2];

    float* out      = (float*)d_out;
    float* out_q    = out;                         // B*D
    float* out_idx  = out + (size_t)B_ROWS * DIM;  // B (indices as float)
    float* out_loss = out_idx + B_ROWS;            // 1

    char* ws = (char*)d_ws;
    const size_t MB = 1024 * 1024;
    float* xc   = (float*)ws;                      // 2 MB
    float* uo   = (float*)(ws + 2 * MB);           // 2 MB
    float* duv  = (float*)(ws + 4 * MB);           // 32 KB
    float* cn   = (float*)(ws + 4 * MB + 64 * 1024);   // 8 KB
    float* pd   = (float*)(ws + 5 * MB);           // 64*8192*4 = 2 MB
    int*   pi   = (int*)(ws + 7 * MB);             // 2 MB
    float* lbuf = (float*)(ws + 9 * MB);           // 32 KB

    rq_prep_codes<<<NCODES / 4, 256, 0, stream>>>(codes, cn);
    rq_prep_rows<<<B_ROWS / 4, 256, 0, stream>>>(x, pq, xc, uo, duv);
    rq_dist_argmin<<<(B_ROWS / ROWS_PER_BLOCK) * NTILES, 256, 0, stream>>>(
        xc, codes, cn, pd, pi);
    rq_epilogue<<<B_ROWS / 4, 256, 0, stream>>>(
        x, codes, uo, duv, pd, pi, out_q, out_idx, lbuf);
    rq_loss_reduce<<<1, 1024, 0, stream>>>(lbuf, out_loss);
}

// Round 3
// 92.990 us; speedup vs baseline: 2.4728x; 1.4492x over previous
//
#include <hip/hip_runtime.h>
#include <math.h>

#define B_ROWS 8192
#define DIM 64
#define NCODES 2048
#define NSPLIT 16                          // code-range splits for dist kernel
#define CODES_PER_SPLIT (NCODES / NSPLIT)  // 128
#define TILES_PER_WAVE (CODES_PER_SPLIT / 16) // 8 tiles of 16 codes
#define EPSF 1e-6f
#define BETA 0.25f
#define V_VAL 0.125f                       // 1/sqrt(64)

typedef __attribute__((ext_vector_type(8))) short sh8;    // 8 bf16 = 4 VGPR
typedef __attribute__((ext_vector_type(4))) float f32x4;  // MFMA acc

__device__ __forceinline__ float wave_sum64(float v) {
#pragma unroll
    for (int m = 32; m >= 1; m >>= 1) v += __shfl_xor(v, m, 64);
    return v;
}

// RNE float -> bf16 bit trick (inputs finite)
__device__ __forceinline__ unsigned short f2bf(float f) {
    unsigned u = __float_as_uint(f);
    unsigned r = (u + 0x7fffu + ((u >> 16) & 1u)) >> 16;
    return (unsigned short)r;
}
__device__ __forceinline__ float bf2f(unsigned short h) {
    return __uint_as_float(((unsigned)h) << 16);
}

// Fragment address helper: frag #((tile16*3 + split)*2 + khalf) is 64 lanes x 16B,
// element (lane, j) = split_s(src[tile16*16 + (lane&15)][khalf*32 + (lane>>4)*8 + j]).
// Writer side: given (row_or_code rc, dim): tile=rc>>4, m=rc&15, h=dim>>5,
// q=(dim>>3)&3, j=dim&7, lane'=q*16+m.

// Kernel A: code norms + bf16x3 split fragments of codes.
__global__ void rq_prep_codes(const float* __restrict__ codes,
                              float* __restrict__ cn,
                              unsigned short* __restrict__ cfrag) {
    int tid = threadIdx.x;
    int lane = tid & 63;                 // dim
    int c = blockIdx.x * 4 + (tid >> 6); // code
    float cv = codes[(size_t)c * DIM + lane];
    float s = wave_sum64(cv * cv);
    if (lane == 0) cn[c] = s;

    unsigned short s0 = f2bf(cv);
    float r = cv - bf2f(s0);
    unsigned short s1 = f2bf(r);
    r -= bf2f(s1);
    unsigned short s2 = f2bf(r);

    int ct = c >> 4, m = c & 15;
    int h = lane >> 5, q = (lane >> 3) & 3, j = lane & 7;
    int lanep = q * 16 + m;
    size_t base = ((size_t)(ct * 3) * 2 + h) * 512 + (size_t)lanep * 8 + j;
    cfrag[base] = s0;
    cfrag[base + 2 * 512] = s1;
    cfrag[base + 4 * 512] = s2;
}

// Kernel B: per-row rotation factors + x_canonical (rank-2, R never formed),
// emitted directly as bf16x3 split fragments in MFMA-A lane order.
__global__ void rq_prep_rows(const float* __restrict__ x,
                             const float* __restrict__ pq,
                             unsigned short* __restrict__ xfrag,
                             float* __restrict__ uo,
                             float* __restrict__ duv) {
    int tid = threadIdx.x;
    int lane = tid & 63;                 // dim
    int r = blockIdx.x * 4 + (tid >> 6); // row
    float xv = x[(size_t)r * DIM + lane];
    float qv = pq[(size_t)r * DIM + lane];
    float n2 = wave_sum64(qv * qv);
    float inv = 1.0f / fmaxf(sqrtf(n2), EPSF);
    float uv = qv * inv;
    float d = V_VAL * wave_sum64(uv);
    float a = wave_sum64(uv * xv);
    float b = V_VAL * wave_sum64(xv);
    float den = 1.0f + d + EPSF;
    float cu = -b + (d * b - a) / den;
    float cv = a - (b - d * a) / den;
    float xcv = xv + uv * cu + V_VAL * cv;

    uo[(size_t)r * DIM + lane] = uv;
    if (lane == 0) duv[r] = d;

    unsigned short s0 = f2bf(xcv);
    float rr = xcv - bf2f(s0);
    unsigned short s1 = f2bf(rr);
    rr -= bf2f(s1);
    unsigned short s2 = f2bf(rr);

    int rt = r >> 4, m = r & 15;
    int h = lane >> 5, q = (lane >> 3) & 3, j = lane & 7;
    int lanep = q * 16 + m;
    size_t base = ((size_t)(rt * 3) * 2 + h) * 512 + (size_t)lanep * 8 + j;
    xfrag[base] = s0;
    xfrag[base + 2 * 512] = s1;
    xfrag[base + 4 * 512] = s2;
}

// Kernel C: MFMA distance scan. Wave = 32 rows (two 16-row A-tile sets,
// bf16x3 resident in 48 VGPRs) x 128 codes (8 tiles of 16). Per tile:
// 6 B-frag dwordx4 loads + 12 MFMAs/rowset chained into one fp32 acc
// (6 split-products x 2 K-halves), then score = cn - 2*dot, running
// lexicographic argmin. End: butterfly over the 16-lane col group.
__global__ __launch_bounds__(256) void rq_dist_mfma(
        const unsigned short* __restrict__ xfrag,
        const unsigned short* __restrict__ cfrag,
        const float* __restrict__ cn,
        float* __restrict__ pd,
        int* __restrict__ pi) {
    int tid = threadIdx.x;
    int lane = tid & 63;
    int w = tid >> 6;
    int rb = blockIdx.x >> 4;     // 64 row-blocks of 128 rows
    int cs = blockIdx.x & (NSPLIT - 1);
    int r0 = rb * 128 + w * 32;
    int rt0 = r0 >> 4;

    const sh8* xf = (const sh8*)xfrag;
    const sh8* cf = (const sh8*)cfrag;

    sh8 afr[2][3][2];
#pragma unroll
    for (int rs = 0; rs < 2; ++rs)
#pragma unroll
        for (int s = 0; s < 3; ++s)
#pragma unroll
            for (int h = 0; h < 2; ++h)
                afr[rs][s][h] = xf[(size_t)(((rt0 + rs) * 3 + s) * 2 + h) * 64 + lane];

    float bv0[4], bv1[4];
    int bi0[4], bi1[4];
#pragma unroll
    for (int i = 0; i < 4; ++i) {
        bv0[i] = INFINITY; bv1[i] = INFINITY;
        bi0[i] = 0x7fffffff; bi1[i] = 0x7fffffff;
    }

    int cbase = cs * CODES_PER_SPLIT;
    for (int t = 0; t < TILES_PER_WAVE; ++t) {
        int c0 = cbase + t * 16;
        int ct = c0 >> 4;
        sh8 bfr[3][2];
#pragma unroll
        for (int s = 0; s < 3; ++s)
#pragma unroll
            for (int h = 0; h < 2; ++h)
                bfr[s][h] = cf[(size_t)((ct * 3 + s) * 2 + h) * 64 + lane];

        f32x4 acc0 = {0.f, 0.f, 0.f, 0.f};
        f32x4 acc1 = {0.f, 0.f, 0.f, 0.f};
#pragma unroll
        for (int h = 0; h < 2; ++h) {
            // smallest-weight terms first: (2,0),(1,1),(0,2) then (1,0),(0,1),(0,0)
            acc0 = __builtin_amdgcn_mfma_f32_16x16x32_bf16(afr[0][2][h], bfr[0][h], acc0, 0, 0, 0);
            acc0 = __builtin_amdgcn_mfma_f32_16x16x32_bf16(afr[0][1][h], bfr[1][h], acc0, 0, 0, 0);
            acc0 = __builtin_amdgcn_mfma_f32_16x16x32_bf16(afr[0][0][h], bfr[2][h], acc0, 0, 0, 0);
            acc0 = __builtin_amdgcn_mfma_f32_16x16x32_bf16(afr[0][1][h], bfr[0][h], acc0, 0, 0, 0);
            acc0 = __builtin_amdgcn_mfma_f32_16x16x32_bf16(afr[0][0][h], bfr[1][h], acc0, 0, 0, 0);
            acc0 = __builtin_amdgcn_mfma_f32_16x16x32_bf16(afr[0][0][h], bfr[0][h], acc0, 0, 0, 0);

            acc1 = __builtin_amdgcn_mfma_f32_16x16x32_bf16(afr[1][2][h], bfr[0][h], acc1, 0, 0, 0);
            acc1 = __builtin_amdgcn_mfma_f32_16x16x32_bf16(afr[1][1][h], bfr[1][h], acc1, 0, 0, 0);
            acc1 = __builtin_amdgcn_mfma_f32_16x16x32_bf16(afr[1][0][h], bfr[2][h], acc1, 0, 0, 0);
            acc1 = __builtin_amdgcn_mfma_f32_16x16x32_bf16(afr[1][1][h], bfr[0][h], acc1, 0, 0, 0);
            acc1 = __builtin_amdgcn_mfma_f32_16x16x32_bf16(afr[1][0][h], bfr[1][h], acc1, 0, 0, 0);
            acc1 = __builtin_amdgcn_mfma_f32_16x16x32_bf16(afr[1][0][h], bfr[0][h], acc1, 0, 0, 0);
        }

        float cnv = cn[c0 + (lane & 15)];
        int idxv = c0 + (lane & 15);
#pragma unroll
        for (int reg = 0; reg < 4; ++reg) {
            float s0 = fmaf(-2.0f, acc0[reg], cnv);
            if (s0 < bv0[reg]) { bv0[reg] = s0; bi0[reg] = idxv; }
            float s1 = fmaf(-2.0f, acc1[reg], cnv);
            if (s1 < bv1[reg]) { bv1[reg] = s1; bi1[reg] = idxv; }
        }
    }

    // Per-row reduction across the 16 cols (lane bits 0-3), lexicographic
    // (val, idx) -> first-occurrence semantics. row = (lane>>4)*4 + reg.
#pragma unroll
    for (int rs = 0; rs < 2; ++rs) {
#pragma unroll
        for (int reg = 0; reg < 4; ++reg) {
            float v = rs ? bv1[reg] : bv0[reg];
            int ix = rs ? bi1[reg] : bi0[reg];
#pragma unroll
            for (int m = 1; m < 16; m <<= 1) {
                float ov = __shfl_xor(v, m, 64);
                int oi = __shfl_xor(ix, m, 64);
                if (ov < v || (ov == v && oi < ix)) { v = ov; ix = oi; }
            }
            int row = r0 + rs * 16 + (lane >> 4) * 4 + reg;
            if ((lane & 15) == reg) {
                pd[(size_t)cs * B_ROWS + row] = v;
                pi[(size_t)cs * B_ROWS + row] = ix;
            }
        }
    }
}

// Kernel D: combine NSPLIT partials per row, gather code, rotate back (R q),
// write quantized + index + per-row loss.
__global__ void rq_epilogue(const float* __restrict__ x,
                            const float* __restrict__ codes,
                            const float* __restrict__ uo,
                            const float* __restrict__ duv,
                            const float* __restrict__ pd,
                            const int* __restrict__ pi,
                            float* __restrict__ out_q,
                            float* __restrict__ out_idx,
                            float* __restrict__ lossbuf) {
    int tid = threadIdx.x;
    int lane = tid & 63;
    int r = blockIdx.x * 4 + (tid >> 6);

    float dmin = INFINITY;
    int imin = 0x7fffffff;
    if (lane < NSPLIT) {
        dmin = pd[(size_t)lane * B_ROWS + r];
        imin = pi[(size_t)lane * B_ROWS + r];
    }
#pragma unroll
    for (int m = 1; m < 64; m <<= 1) {
        float od = __shfl_xor(dmin, m, 64);
        int oi = __shfl_xor(imin, m, 64);
        if (od < dmin || (od == dmin && oi < imin)) { dmin = od; imin = oi; }
    }
    int idx = imin;

    float qc = codes[(size_t)idx * DIM + lane];
    float uv = uo[(size_t)r * DIM + lane];
    float xv = x[(size_t)r * DIM + lane];
    float d = duv[r];

    float aq = wave_sum64(uv * qc);
    float bq = V_VAL * wave_sum64(qc);
    float den = 1.0f + d + EPSF;
    float cu = bq + (d * bq - aq) / den;
    float cv = -aq - (bq - d * aq) / den;
    float qout = qc + uv * cu + V_VAL * cv;
    out_q[(size_t)r * DIM + lane] = qout;

    float diff = xv - qc;
    float l = wave_sum64(diff * diff);
    if (lane == 0) {
        out_idx[r] = (float)idx;
        lossbuf[r] = l;
    }
}

// Kernel E: single-block sum of per-row losses -> scaled scalar.
__global__ void rq_loss_reduce(const float* __restrict__ lossbuf,
                               float* __restrict__ out_loss) {
    __shared__ float part[16];
    int tid = threadIdx.x;  // 1024 threads
    float s = 0.f;
#pragma unroll
    for (int i = 0; i < B_ROWS / 1024; ++i) s += lossbuf[tid + i * 1024];
    s = wave_sum64(s);
    if ((tid & 63) == 0) part[tid >> 6] = s;
    __syncthreads();
    if (tid < 64) {
        float v = (tid < 16) ? part[tid] : 0.f;
        v = wave_sum64(v);
        if (tid == 0) *out_loss = v * (1.0f + BETA) * (1.0f / (float)B_ROWS);
    }
}

extern "C" void kernel_launch(void* const* d_in, const int* in_sizes, int n_in,
                              void* d_out, int out_size, void* d_ws, size_t ws_size,
                              hipStream_t stream) {
    const float* x     = (const float*)d_in[0];
    const float* pq    = (const float*)d_in[1];
    const float* codes = (const float*)d_in[2];

    float* out      = (float*)d_out;
    float* out_q    = out;                         // B*D
    float* out_idx  = out + (size_t)B_ROWS * DIM;  // B
    float* out_loss = out_idx + B_ROWS;            // 1

    char* ws = (char*)d_ws;
    const size_t MB = 1024 * 1024;
    float* uo            = (float*)ws;                          // 2 MB
    float* duv           = (float*)(ws + 2 * MB);               // 32 KB
    float* cn            = (float*)(ws + 2 * MB + 64 * 1024);   // 8 KB
    unsigned short* xfrg = (unsigned short*)(ws + 3 * MB);      // 3 MB
    unsigned short* cfrg = (unsigned short*)(ws + 6 * MB);      // 768 KB
    float* pd            = (float*)(ws + 7 * MB);               // 512 KB
    int*   pi            = (int*)(ws + 7 * MB + 512 * 1024);    // 512 KB
    float* lbuf          = (float*)(ws + 8 * MB);               // 32 KB

    rq_prep_codes<<<NCODES / 4, 256, 0, stream>>>(codes, cn, cfrg);
    rq_prep_rows<<<B_ROWS / 4, 256, 0, stream>>>(x, pq, xfrg, uo, duv);
    rq_dist_mfma<<<64 * NSPLIT, 256, 0, stream>>>(xfrg, cfrg, cn, pd, pi);
    rq_epilogue<<<B_ROWS / 4, 256, 0, stream>>>(
        x, codes, uo, duv, pd, pi, out_q, out_idx, lbuf);
    rq_loss_reduce<<<1, 1024, 0, stream>>>(lbuf, out_loss);
}